// Round 1
// baseline (336.272 us; speedup 1.0000x reference)
//
#include <hip/hip_runtime.h>

typedef __bf16 bf16x8 __attribute__((ext_vector_type(8)));
typedef float  f32x4  __attribute__((ext_vector_type(4)));

constexpr int BATCH = 65536;
constexpr int OBS   = 20;
constexpr int PRED  = 12;
constexpr int BT    = 128;   // batch rows per workgroup
constexpr int AST   = 136;   // A-row stride in bf16 elems (128 + 8 pad -> conflict-free b128)

static_assert(BATCH % BT == 0, "grid must tile batch exactly");

template <int N> struct ic { static constexpr int v = N; };

__device__ __forceinline__ float fast_sigmoid(float x) {
    // 1 / (1 + 2^(-x*log2e))
    float e = __builtin_amdgcn_exp2f(-1.4426950408889634f * x);
    return __builtin_amdgcn_rcpf(1.0f + e);
}
__device__ __forceinline__ float fast_tanh(float x) {
    // 1 - 2/(2^(2x*log2e) + 1); saturates correctly via inf/0
    float e = __builtin_amdgcn_exp2f(2.8853900817779268f * x);
    return 1.0f - 2.0f * __builtin_amdgcn_rcpf(1.0f + e);
}

struct SmallW {
    float bcomb_e[256];
    float bcomb_d[256];
    float wemb[128];   // W_emb [64][2]
    float bemb[64];
    float wfc[128];    // W_fc [2][64]
    float bfc[2];
};

__global__ __launch_bounds__(256, 2)
void vanilla_lstm(const float* __restrict__ obs,
                  const float* __restrict__ W_emb, const float* __restrict__ b_emb,
                  const float* __restrict__ Wih_e, const float* __restrict__ Whh_e,
                  const float* __restrict__ bih_e, const float* __restrict__ bhh_e,
                  const float* __restrict__ Wih_d, const float* __restrict__ Whh_d,
                  const float* __restrict__ bih_d, const float* __restrict__ bhh_d,
                  const float* __restrict__ W_fc,  const float* __restrict__ b_fc,
                  float* __restrict__ out)
{
    // A = [x | h] concat, bf16, padded row stride (bank-conflict-free fragments)
    __shared__ __align__(16) __bf16 As[BT * AST];
    __shared__ __align__(16) float  obs_s[BT * OBS * 2];
    __shared__ SmallW sw;

    const int tid  = threadIdx.x;
    const int wv   = tid >> 6;     // wave 0..3
    const int lane = tid & 63;
    const int m    = lane & 15;    // MFMA n/m lane index
    const int q    = lane >> 4;    // MFMA quad
    const int wblk = wv * 16;      // this wave's 16 gate-columns (per gate)
    const size_t gRow0 = (size_t)blockIdx.x * BT;

    // ---- stage obs tile (coalesced float4: 128 rows x 40 floats) ----
    {
        const float4* src = (const float4*)(obs + gRow0 * (OBS * 2));
        float4* dst = (float4*)obs_s;
        #pragma unroll
        for (int i = 0; i < (BT * OBS * 2 / 4) / 256; ++i)   // 5 iters
            dst[tid + i * 256] = src[tid + i * 256];
    }
    // ---- stage small weights / combined biases ----
    {
        sw.bcomb_e[tid] = bih_e[tid] + bhh_e[tid];
        sw.bcomb_d[tid] = bih_d[tid] + bhh_d[tid];
        if (tid < 128) { sw.wemb[tid] = W_emb[tid]; sw.wfc[tid] = W_fc[tid]; }
        if (tid < 64)  sw.bemb[tid] = b_emb[tid];
        if (tid < 2)   sw.bfc[tid]  = b_fc[tid];
    }
    // ---- zero A (h half must start at 0) ----
    {
        uint4 z; z.x = z.y = z.z = z.w = 0u;
        uint4* p = (uint4*)As;
        constexpr int NV = BT * AST * 2 / 16;  // 2176
        #pragma unroll
        for (int i = 0; i < (NV + 255) / 256; ++i) {
            int idx = tid + i * 256;
            if (idx < NV) p[idx] = z;
        }
    }

    // ---- per-wave B fragments in registers: ct = wv + 4*c (c = i,f,g,o), kt = 0..3 ----
    bf16x8 bfr[4][4];
    auto load_bfr = [&](const float* Wih, const float* Whh) {
        #pragma unroll
        for (int c = 0; c < 4; ++c) {
            const int n = (wv + 4 * c) * 16 + m;
            #pragma unroll
            for (int kt = 0; kt < 4; ++kt) {
                const float* s = (kt < 2) ? (Wih + n * 64 + kt * 32 + q * 8)
                                          : (Whh + n * 64 + (kt - 2) * 32 + q * 8);
                bf16x8 v;
                #pragma unroll
                for (int j = 0; j < 8; ++j) v[j] = (__bf16)s[j];
                bfr[c][kt] = v;
            }
        }
    };
    load_bfr(Wih_e, Whh_e);

    // c-state: rows (chunk*64 + rt*16 + q*4 + r), col = wblk + m
    f32x4 cst[8];
    #pragma unroll
    for (int i = 0; i < 8; ++i) cst[i] = f32x4{0.f, 0.f, 0.f, 0.f};

    __syncthreads();

    float bias[4];
    #pragma unroll
    for (int c = 0; c < 4; ++c) bias[c] = sw.bcomb_e[(wv + 4 * c) * 16 + m];

    // encoder embedding write: lane -> row, wave -> 16 cols
    auto write_emb_enc = [&](int row, int t) {
        const float o0 = obs_s[row * (OBS * 2) + t * 2 + 0];
        const float o1 = obs_s[row * (OBS * 2) + t * 2 + 1];
        #pragma unroll
        for (int h8 = 0; h8 < 2; ++h8) {
            bf16x8 v;
            #pragma unroll
            for (int j = 0; j < 8; ++j) {
                const int e = wblk + h8 * 8 + j;
                float x = o0 * sw.wemb[2 * e] + o1 * sw.wemb[2 * e + 1] + sw.bemb[e];
                v[j] = (__bf16)fmaxf(x, 0.f);
            }
            *(bf16x8*)&As[row * AST + wblk + h8 * 8] = v;
        }
    };

    // initial x0 = relu(emb(obs[:,0]))
    write_emb_enc(lane, 0);
    write_emb_enc(64 + lane, 0);
    __syncthreads();

    // one 64-row chunk: GEMM -> barrier -> cell update (+h writeback)
    auto do_chunk = [&](auto C) {
        constexpr int chunk = decltype(C)::v;
        const int cb = chunk * 64;
        f32x4 acc[4][4];
        #pragma unroll
        for (int rt = 0; rt < 4; ++rt) {
            #pragma unroll
            for (int c = 0; c < 4; ++c)
                acc[rt][c] = f32x4{bias[c], bias[c], bias[c], bias[c]};
        }
        #pragma unroll
        for (int kt = 0; kt < 4; ++kt) {
            bf16x8 af[4];
            #pragma unroll
            for (int rt = 0; rt < 4; ++rt)
                af[rt] = *(const bf16x8*)&As[(cb + rt * 16 + m) * AST + kt * 32 + q * 8];
            #pragma unroll
            for (int rt = 0; rt < 4; ++rt) {
                #pragma unroll
                for (int c = 0; c < 4; ++c)
                    acc[rt][c] = __builtin_amdgcn_mfma_f32_16x16x32_bf16(
                        af[rt], bfr[c][kt], acc[rt][c], 0, 0, 0);
            }
        }
        __syncthreads();   // all waves done reading A rows of this chunk
        #pragma unroll
        for (int rt = 0; rt < 4; ++rt) {
            #pragma unroll
            for (int r = 0; r < 4; ++r) {
                const float gi = acc[rt][0][r];
                const float gf = acc[rt][1][r];
                const float gg = acc[rt][2][r];
                const float go = acc[rt][3][r];
                const float cPrev = cst[chunk * 4 + rt][r];
                const float cNew  = fast_sigmoid(gf) * cPrev + fast_sigmoid(gi) * fast_tanh(gg);
                const float hNew  = fast_sigmoid(go) * fast_tanh(cNew);
                cst[chunk * 4 + rt][r] = cNew;
                As[(cb + rt * 16 + q * 4 + r) * AST + 64 + wblk + m] = (__bf16)hNew;
            }
        }
    };

    // ================= encoder =================
    for (int t = 0; t < OBS; ++t) {
        do_chunk(ic<0>{});
        if (t + 1 < OBS) write_emb_enc(lane, t + 1);        // rows 0..63 x-half for t+1
        do_chunk(ic<1>{});
        if (t + 1 < OBS) write_emb_enc(64 + lane, t + 1);   // rows 64..127
    }
    // A.x now holds emb(obs[:,19]) == dec_in; h,c carry over.

    // ================= decoder =================
    load_bfr(Wih_d, Whh_d);
    #pragma unroll
    for (int c = 0; c < 4; ++c) bias[c] = sw.bcomb_d[(wv + 4 * c) * 16 + m];

    for (int td = 0; td < PRED; ++td) {
        do_chunk(ic<0>{});
        do_chunk(ic<1>{});
        __syncthreads();           // full h visible
        if (tid < BT) {
            const int row = tid;
            float p0 = sw.bfc[0], p1 = sw.bfc[1];
            #pragma unroll
            for (int e8 = 0; e8 < 8; ++e8) {
                bf16x8 hv = *(const bf16x8*)&As[row * AST + 64 + e8 * 8];
                #pragma unroll
                for (int j = 0; j < 8; ++j) {
                    const float h = (float)hv[j];
                    p0 += h * sw.wfc[e8 * 8 + j];
                    p1 += h * sw.wfc[64 + e8 * 8 + j];
                }
            }
            const size_t ob = ((gRow0 + row) * PRED + td) * 2;
            out[ob + 0] = p0;
            out[ob + 1] = p1;
            if (td + 1 < PRED) {   // next x = relu(emb(pred))
                #pragma unroll
                for (int e8 = 0; e8 < 8; ++e8) {
                    bf16x8 v;
                    #pragma unroll
                    for (int j = 0; j < 8; ++j) {
                        const int e = e8 * 8 + j;
                        float x = p0 * sw.wemb[2 * e] + p1 * sw.wemb[2 * e + 1] + sw.bemb[e];
                        v[j] = (__bf16)fmaxf(x, 0.f);
                    }
                    *(bf16x8*)&As[row * AST + e8 * 8] = v;
                }
            }
        }
        __syncthreads();
    }
}

extern "C" void kernel_launch(void* const* d_in, const int* in_sizes, int n_in,
                              void* d_out, int out_size, void* d_ws, size_t ws_size,
                              hipStream_t stream) {
    (void)in_sizes; (void)n_in; (void)d_ws; (void)ws_size; (void)out_size;
    const float* obs   = (const float*)d_in[0];
    const float* W_emb = (const float*)d_in[1];
    const float* b_emb = (const float*)d_in[2];
    const float* Wih_e = (const float*)d_in[3];
    const float* Whh_e = (const float*)d_in[4];
    const float* bih_e = (const float*)d_in[5];
    const float* bhh_e = (const float*)d_in[6];
    const float* Wih_d = (const float*)d_in[7];
    const float* Whh_d = (const float*)d_in[8];
    const float* bih_d = (const float*)d_in[9];
    const float* bhh_d = (const float*)d_in[10];
    const float* W_fc  = (const float*)d_in[11];
    const float* b_fc  = (const float*)d_in[12];
    float* o = (float*)d_out;

    dim3 grid(BATCH / BT), block(256);
    hipLaunchKernelGGL(vanilla_lstm, grid, block, 0, stream,
                       obs, W_emb, b_emb, Wih_e, Whh_e, bih_e, bhh_e,
                       Wih_d, Whh_d, bih_d, bhh_d, W_fc, b_fc, o);
}

// Round 2
// 307.361 us; speedup vs baseline: 1.0941x; 1.0941x over previous
//
#include <hip/hip_runtime.h>

typedef __bf16 bf16x8 __attribute__((ext_vector_type(8)));
typedef __bf16 bf16x4 __attribute__((ext_vector_type(4)));
typedef float  f32x4  __attribute__((ext_vector_type(4)));
typedef float  f32x2  __attribute__((ext_vector_type(2)));

constexpr int BATCH = 65536;
constexpr int OBS   = 20;
constexpr int PRED  = 12;
constexpr int BT    = 128;   // batch rows per workgroup
constexpr int AST   = 136;   // A-row stride in bf16 elems (128 + 8 pad)

__device__ __forceinline__ float sigm(float x) {
    return __builtin_amdgcn_rcpf(1.0f + __builtin_amdgcn_exp2f(x * -1.4426950408889634f));
}
__device__ __forceinline__ float tanh_(float x) {
    return 1.0f - 2.0f * __builtin_amdgcn_rcpf(1.0f + __builtin_amdgcn_exp2f(x * 2.8853900817779268f));
}

struct SmallW {
    float  bcomb_e[256];
    float  bcomb_d[256];
    float4 embc[64];     // {w_emb[e][0], w_emb[e][1], b_emb[e], 0}
    float  wfc[128];     // W_fc [2][64]
    float  bfc[2];
};

__global__ __launch_bounds__(256, 2)
void vanilla_lstm(const float* __restrict__ obs,
                  const float* __restrict__ W_emb, const float* __restrict__ b_emb,
                  const float* __restrict__ Wih_e, const float* __restrict__ Whh_e,
                  const float* __restrict__ bih_e, const float* __restrict__ bhh_e,
                  const float* __restrict__ Wih_d, const float* __restrict__ Whh_d,
                  const float* __restrict__ bih_d, const float* __restrict__ bhh_d,
                  const float* __restrict__ W_fc,  const float* __restrict__ b_fc,
                  float* __restrict__ out)
{
    __shared__ __align__(16) __bf16 As[BT * AST];   // [x(64) | h(64)] bf16, padded
    __shared__ __align__(16) float  pred_s[BT * 2];
    __shared__ SmallW sw;

    const int tid  = threadIdx.x;
    const int wv   = tid >> 6;
    const int lane = tid & 63;
    const int m    = lane & 15;
    const int q    = lane >> 4;
    const int wblk = wv * 16;          // this wave's 16 hidden cols
    const size_t gRow0 = (size_t)blockIdx.x * BT;

    // ---- stage small weights ----
    sw.bcomb_e[tid] = bih_e[tid] + bhh_e[tid];
    sw.bcomb_d[tid] = bih_d[tid] + bhh_d[tid];
    if (tid < 64)  sw.embc[tid] = make_float4(W_emb[2 * tid], W_emb[2 * tid + 1], b_emb[tid], 0.f);
    if (tid < 128) sw.wfc[tid]  = W_fc[tid];
    if (tid < 2)   sw.bfc[tid]  = b_fc[tid];

    // ---- zero As (h half must start at 0; x half overwritten below) ----
    {
        uint4 z; z.x = z.y = z.z = z.w = 0u;
        uint4* p = (uint4*)As;
        constexpr int NV = BT * AST * 2 / 16;   // 2176
        #pragma unroll
        for (int i = 0; i < NV / 256; ++i) p[tid + i * 256] = z;
        if (tid < (NV % 256)) p[tid + (NV / 256) * 256] = z;
    }

    // ---- weights in registers: A-operand fragments, gatecol n = c*64 + wblk + m ----
    bf16x8 bfr[4][4];
    auto load_bfr = [&](const float* Wih, const float* Whh) {
        #pragma unroll
        for (int c = 0; c < 4; ++c) {
            const int n = c * 64 + wblk + m;
            #pragma unroll
            for (int kt = 0; kt < 4; ++kt) {
                const float* s = (kt < 2) ? (Wih + n * 64 + kt * 32 + q * 8)
                                          : (Whh + n * 64 + (kt - 2) * 32 + q * 8);
                float4 a = *(const float4*)s;
                float4 b = *(const float4*)(s + 4);
                bf16x8 v;
                v[0] = (__bf16)a.x; v[1] = (__bf16)a.y; v[2] = (__bf16)a.z; v[3] = (__bf16)a.w;
                v[4] = (__bf16)b.x; v[5] = (__bf16)b.y; v[6] = (__bf16)b.z; v[7] = (__bf16)b.w;
                bfr[c][kt] = v;
            }
        }
    };
    load_bfr(Wih_e, Whh_e);

    // c-state: per nt one batch row (m), hidden cols wblk + q*4 + r
    f32x4 cst[8];
    #pragma unroll
    for (int i = 0; i < 8; ++i) cst[i] = f32x4{0.f, 0.f, 0.f, 0.f};

    __syncthreads();

    f32x4 bias4[4];
    auto load_bias = [&](const float* bc) {
        #pragma unroll
        for (int c = 0; c < 4; ++c)
            bias4[c] = *(const f32x4*)&bc[c * 64 + wblk + q * 4];
    };
    load_bias(sw.bcomb_e);

    f32x4 acc[4][4];   // [ntile][gate], reused: consumed by update, refilled by gemm

    // G^T GEMM: D[gatecol=q*4+r][batchrow=m]; chunk = 64-row half
    auto gemm = [&](int chunk) {
        #pragma unroll
        for (int nt = 0; nt < 4; ++nt)
            #pragma unroll
            for (int c = 0; c < 4; ++c)
                acc[nt][c] = bias4[c];
        #pragma unroll
        for (int kt = 0; kt < 4; ++kt) {
            bf16x8 af[4];
            #pragma unroll
            for (int nt = 0; nt < 4; ++nt)
                af[nt] = *(const bf16x8*)&As[(chunk * 64 + nt * 16 + m) * AST + kt * 32 + q * 8];
            #pragma unroll
            for (int nt = 0; nt < 4; ++nt)
                #pragma unroll
                for (int c = 0; c < 4; ++c)
                    acc[nt][c] = __builtin_amdgcn_mfma_f32_16x16x32_bf16(
                        bfr[c][kt], af[nt], acc[nt][c], 0, 0, 0);
        }
    };

    // cell update + packed b64 h writeback
    auto update = [&](int chunk) {
        #pragma unroll
        for (int nt = 0; nt < 4; ++nt) {
            const int row = chunk * 64 + nt * 16 + m;
            f32x4 ci = cst[chunk * 4 + nt];
            bf16x4 h4;
            #pragma unroll
            for (int r = 0; r < 4; ++r) {
                const float cN = sigm(acc[nt][1][r]) * ci[r]
                               + sigm(acc[nt][0][r]) * tanh_(acc[nt][2][r]);
                ci[r] = cN;
                h4[r] = (__bf16)(sigm(acc[nt][3][r]) * tanh_(cN));
            }
            cst[chunk * 4 + nt] = ci;
            *(bf16x4*)&As[row * AST + 64 + wblk + q * 4] = h4;
        }
    };

    auto emb_row = [&](int row, float o0, float o1) {
        #pragma unroll
        for (int h8 = 0; h8 < 2; ++h8) {
            bf16x8 v;
            #pragma unroll
            for (int j = 0; j < 8; ++j) {
                float4 wc = sw.embc[wblk + h8 * 8 + j];
                v[j] = (__bf16)fmaxf(fmaf(o0, wc.x, fmaf(o1, wc.y, wc.z)), 0.f);
            }
            *(bf16x8*)&As[row * AST + wblk + h8 * 8] = v;
        }
    };

    const float* obr0 = obs + (gRow0 + lane) * (OBS * 2);
    const float* obr1 = obs + (gRow0 + 64 + lane) * (OBS * 2);

    // prologue: x0 = relu(emb(obs[:,0])), then first GEMM on rows 0..63
    {
        f32x2 o0 = *(const f32x2*)obr0;
        f32x2 o1 = *(const f32x2*)obr1;
        emb_row(lane, o0[0], o0[1]);
        emb_row(64 + lane, o1[0], o1[1]);
    }
    __syncthreads();
    gemm(0);

    // ================= encoder (2 barriers/step, acc-reuse pipeline) =================
    for (int t = 0; t < OBS; ++t) {
        __syncthreads();                               // ph A
        f32x2 on0{0.f, 0.f};
        if (t + 1 < OBS) on0 = *(const f32x2*)(obr0 + (t + 1) * 2);
        update(0);                                     // consume acc (C0, step t)
        gemm(1);                                       // refill acc (C1, step t)
        if (t + 1 < OBS) emb_row(lane, on0[0], on0[1]);
        __syncthreads();                               // ph B
        f32x2 on1{0.f, 0.f};
        if (t + 1 < OBS) on1 = *(const f32x2*)(obr1 + (t + 1) * 2);
        update(1);                                     // consume acc (C1, step t)
        if (t + 1 < OBS) {
            gemm(0);                                   // refill acc (C0, step t+1)
            emb_row(64 + lane, on1[0], on1[1]);
        }
    }

    // ================= decoder =================
    load_bfr(Wih_d, Whh_d);
    load_bias(sw.bcomb_d);
    gemm(0);   // td=0, C0: x = emb(obs[:,19]) already in As; h C0 from enc t=19

    auto pred_phase = [&](int chunk, int td) {
        const int prow = chunk * 64 + (tid >> 2);
        const int comp = (tid >> 1) & 1, half = tid & 1;
        const int cb = half * 32;
        float p = 0.f;
        #pragma unroll
        for (int e8 = 0; e8 < 4; ++e8) {
            bf16x8 hv = *(const bf16x8*)&As[prow * AST + 64 + cb + e8 * 8];
            f32x4 w0 = *(const f32x4*)&sw.wfc[comp * 64 + cb + e8 * 8];
            f32x4 w1 = *(const f32x4*)&sw.wfc[comp * 64 + cb + e8 * 8 + 4];
            p += (float)hv[0] * w0[0] + (float)hv[1] * w0[1] + (float)hv[2] * w0[2] + (float)hv[3] * w0[3]
               + (float)hv[4] * w1[0] + (float)hv[5] * w1[1] + (float)hv[6] * w1[2] + (float)hv[7] * w1[3];
        }
        p += __shfl_xor(p, 1, 64);
        if (half == 0) {
            p += sw.bfc[comp];
            pred_s[prow * 2 + comp] = p;
            out[((gRow0 + prow) * PRED + td) * 2 + comp] = p;
        }
    };
    auto emb_dec = [&](int chunk) {
        const int row = chunk * 64 + lane;
        f32x2 pv = *(const f32x2*)&pred_s[row * 2];
        emb_row(row, pv[0], pv[1]);
    };

    for (int td = 0; td < PRED; ++td) {
        __syncthreads();                 // ph1
        update(0);                       // consume acc (C0, td)
        gemm(1);                         // refill acc (C1, td)
        __syncthreads();                 // ph2
        update(1);                       // consume acc (C1, td)
        pred_phase(0, td);               // rows 0..63: pred -> pred_s, out
        __syncthreads();                 // ph3
        pred_phase(1, td);               // rows 64..127
        if (td + 1 < PRED) emb_dec(0);   // x(td+1) rows 0..63
        __syncthreads();                 // ph4
        if (td + 1 < PRED) {
            emb_dec(1);                  // x(td+1) rows 64..127
            gemm(0);                     // refill acc (C0, td+1)
        }
    }
}

extern "C" void kernel_launch(void* const* d_in, const int* in_sizes, int n_in,
                              void* d_out, int out_size, void* d_ws, size_t ws_size,
                              hipStream_t stream) {
    (void)in_sizes; (void)n_in; (void)d_ws; (void)ws_size; (void)out_size;
    const float* obs   = (const float*)d_in[0];
    const float* W_emb = (const float*)d_in[1];
    const float* b_emb = (const float*)d_in[2];
    const float* Wih_e = (const float*)d_in[3];
    const float* Whh_e = (const float*)d_in[4];
    const float* bih_e = (const float*)d_in[5];
    const float* bhh_e = (const float*)d_in[6];
    const float* Wih_d = (const float*)d_in[7];
    const float* Whh_d = (const float*)d_in[8];
    const float* bih_d = (const float*)d_in[9];
    const float* bhh_d = (const float*)d_in[10];
    const float* W_fc  = (const float*)d_in[11];
    const float* b_fc  = (const float*)d_in[12];
    float* o = (float*)d_out;

    dim3 grid(BATCH / BT), block(256);
    hipLaunchKernelGGL(vanilla_lstm, grid, block, 0, stream,
                       obs, W_emb, b_emb, Wih_e, Whh_e, bih_e, bhh_e,
                       Wih_d, Whh_d, bih_d, bhh_d, W_fc, b_fc, o);
}

// Round 3
// 285.214 us; speedup vs baseline: 1.1790x; 1.0776x over previous
//
#include <hip/hip_runtime.h>

typedef __bf16 bf16x8 __attribute__((ext_vector_type(8)));
typedef __bf16 bf16x4 __attribute__((ext_vector_type(4)));
typedef float  f32x4  __attribute__((ext_vector_type(4)));
typedef float  f32x2  __attribute__((ext_vector_type(2)));

constexpr int BATCH = 65536;
constexpr int OBS   = 20;
constexpr int PRED  = 12;
constexpr int BT    = 128;   // batch rows per workgroup
constexpr int AST   = 136;   // A-row stride in bf16 elems (128 + 8 pad)

// gate pre-scales folded into weights/biases:
// i,f,o scaled by -log2(e)  -> sigmoid(x) = rcp(1 + exp2(gate))
// g     scaled by +2*log2(e)-> tanh(x)    = (exp2(gate)-1)/(exp2(gate)+1)
constexpr float SIO = -1.4426950408889634f;
constexpr float SG  =  2.8853900817779268f;

__device__ __forceinline__ float exp2_(float x) { return __builtin_amdgcn_exp2f(x); }
__device__ __forceinline__ float rcp_(float x)  { return __builtin_amdgcn_rcpf(x); }

struct SmallW {
    float  bcomb_e[256];
    float  bcomb_d[256];
    float4 embc[64];     // {w_emb[e][0], w_emb[e][1], b_emb[e], 0}
    float  wfc[128];     // W_fc [2][64]
    float  bfc[2];
};

__global__ __launch_bounds__(256, 2)
void vanilla_lstm(const float* __restrict__ obs,
                  const float* __restrict__ W_emb, const float* __restrict__ b_emb,
                  const float* __restrict__ Wih_e, const float* __restrict__ Whh_e,
                  const float* __restrict__ bih_e, const float* __restrict__ bhh_e,
                  const float* __restrict__ Wih_d, const float* __restrict__ Whh_d,
                  const float* __restrict__ bih_d, const float* __restrict__ bhh_d,
                  const float* __restrict__ W_fc,  const float* __restrict__ b_fc,
                  float* __restrict__ out)
{
    __shared__ __align__(16) __bf16 As[BT * AST];   // [x(64) | h(64)] bf16, padded
    __shared__ __align__(16) float  pred_s[BT * 2];
    __shared__ SmallW sw;

    const int tid  = threadIdx.x;
    const int wv   = tid >> 6;
    const int lane = tid & 63;
    const int m    = lane & 15;
    const int q    = lane >> 4;
    const int wblk = wv * 16;          // this wave's 16 hidden cols
    const size_t gRow0 = (size_t)blockIdx.x * BT;

    // ---- stage small weights ----
    sw.bcomb_e[tid] = bih_e[tid] + bhh_e[tid];
    sw.bcomb_d[tid] = bih_d[tid] + bhh_d[tid];
    if (tid < 64)  sw.embc[tid] = make_float4(W_emb[2 * tid], W_emb[2 * tid + 1], b_emb[tid], 0.f);
    if (tid < 128) sw.wfc[tid]  = W_fc[tid];
    if (tid < 2)   sw.bfc[tid]  = b_fc[tid];

    // ---- zero As (h half must start at 0; x half overwritten below) ----
    {
        uint4 z; z.x = z.y = z.z = z.w = 0u;
        uint4* p = (uint4*)As;
        constexpr int NV = BT * AST * 2 / 16;   // 2176
        #pragma unroll
        for (int i = 0; i < NV / 256; ++i) p[tid + i * 256] = z;
        if (tid < (NV % 256)) p[tid + (NV / 256) * 256] = z;
    }

    // ---- weights in registers (prescaled): A-operand frags, gatecol n = c*64 + wblk + m ----
    bf16x8 bfr[4][4];
    auto load_bfr = [&](const float* Wih, const float* Whh) {
        #pragma unroll
        for (int c = 0; c < 4; ++c) {
            const float sc = (c == 2) ? SG : SIO;
            const int n = c * 64 + wblk + m;
            #pragma unroll
            for (int kt = 0; kt < 4; ++kt) {
                const float* s = (kt < 2) ? (Wih + n * 64 + kt * 32 + q * 8)
                                          : (Whh + n * 64 + (kt - 2) * 32 + q * 8);
                float4 a = *(const float4*)s;
                float4 b = *(const float4*)(s + 4);
                bf16x8 v;
                v[0] = (__bf16)(sc * a.x); v[1] = (__bf16)(sc * a.y);
                v[2] = (__bf16)(sc * a.z); v[3] = (__bf16)(sc * a.w);
                v[4] = (__bf16)(sc * b.x); v[5] = (__bf16)(sc * b.y);
                v[6] = (__bf16)(sc * b.z); v[7] = (__bf16)(sc * b.w);
                bfr[c][kt] = v;
            }
        }
    };
    load_bfr(Wih_e, Whh_e);

    // c-state: idx = chunk*4 + half*2 + nt; row = chunk*64+(half*2+nt)*16+m, cols wblk+q*4+r
    f32x4 cst[8];
    #pragma unroll
    for (int i = 0; i < 8; ++i) cst[i] = f32x4{0.f, 0.f, 0.f, 0.f};

    __syncthreads();

    f32x4 bias4[4];
    auto load_bias = [&](const float* bc) {
        #pragma unroll
        for (int c = 0; c < 4; ++c) {
            const float sc = (c == 2) ? SG : SIO;
            f32x4 b = *(const f32x4*)&bc[c * 64 + wblk + q * 4];
            bias4[c] = f32x4{sc * b[0], sc * b[1], sc * b[2], sc * b[3]};
        }
    };
    load_bias(sw.bcomb_e);

    // two independent 32-row acc sets per chunk -> no WAR between update(a) and gemm(b)
    f32x4 acc[2][2][4];   // [half][nt][gate]

    auto gemm_sub = [&](int chunk, int half) {
        #pragma unroll
        for (int nt = 0; nt < 2; ++nt)
            #pragma unroll
            for (int c = 0; c < 4; ++c)
                acc[half][nt][c] = bias4[c];
        #pragma unroll
        for (int kt = 0; kt < 4; ++kt) {
            bf16x8 af[2];
            #pragma unroll
            for (int nt = 0; nt < 2; ++nt)
                af[nt] = *(const bf16x8*)&As[(chunk * 64 + (half * 2 + nt) * 16 + m) * AST + kt * 32 + q * 8];
            #pragma unroll
            for (int nt = 0; nt < 2; ++nt)
                #pragma unroll
                for (int c = 0; c < 4; ++c)
                    acc[half][nt][c] = __builtin_amdgcn_mfma_f32_16x16x32_bf16(
                        bfr[c][kt], af[nt], acc[half][nt][c], 0, 0, 0);
        }
    };

    // cell update: 5 exp + 3 rcp per cell (combined-rcp identity, prescaled gates)
    auto update_sub = [&](int chunk, int half) {
        #pragma unroll
        for (int nt = 0; nt < 2; ++nt) {
            const int idx = chunk * 4 + half * 2 + nt;
            const int row = chunk * 64 + (half * 2 + nt) * 16 + m;
            f32x4 ci = cst[idx];
            bf16x4 h4;
            #pragma unroll
            for (int r = 0; r < 4; ++r) {
                const float gi = acc[half][nt][0][r];
                const float gf = acc[half][nt][1][r];
                const float gg = acc[half][nt][2][r];
                const float go = acc[half][nt][3][r];
                const float Ef = exp2_(gf);                     // = exp(-f)
                const float a  = ci[r] * rcp_(1.0f + Ef);       // sigmoid(f)*c
                const float Ei = exp2_(gi);                     // = exp(-i)
                const float Eg = exp2_(fminf(fmaxf(gg, -80.f), 80.f));  // = exp(2g)
                const float d1 = 1.0f + Ei;
                const float r1 = rcp_(fmaf(d1, Eg, d1));        // 1/[(1+Ei)(1+Eg)]
                const float cN = fmaf(Eg - 1.0f, r1, a);        // sig(i)*tanh(g) + sig(f)*c
                const float Eo = exp2_(go);                     // = exp(-o)
                const float Ec = exp2_(fminf(fmaxf(cN * SG, -80.f), 80.f)); // = exp(2c)
                const float d2 = 1.0f + Eo;
                const float r2 = rcp_(fmaf(d2, Ec, d2));
                const float h  = (Ec - 1.0f) * r2;              // sig(o)*tanh(cN)
                ci[r] = cN;
                h4[r] = (__bf16)h;
            }
            cst[idx] = ci;
            *(bf16x4*)&As[row * AST + 64 + wblk + q * 4] = h4;
        }
    };

    auto emb_row = [&](int row, float o0, float o1) {
        #pragma unroll
        for (int h8 = 0; h8 < 2; ++h8) {
            bf16x8 v;
            #pragma unroll
            for (int j = 0; j < 8; ++j) {
                float4 wc = sw.embc[wblk + h8 * 8 + j];
                v[j] = (__bf16)fmaxf(fmaf(o0, wc.x, fmaf(o1, wc.y, wc.z)), 0.f);
            }
            *(bf16x8*)&As[row * AST + wblk + h8 * 8] = v;
        }
    };

    const float* obr0 = obs + (gRow0 + lane) * (OBS * 2);
    const float* obr1 = obs + (gRow0 + 64 + lane) * (OBS * 2);

    // prologue: x0 = relu(emb(obs[:,0])), then first GEMM on rows 0..63
    {
        f32x2 o0 = *(const f32x2*)obr0;
        f32x2 o1 = *(const f32x2*)obr1;
        emb_row(lane, o0[0], o0[1]);
        emb_row(64 + lane, o1[0], o1[1]);
    }
    __syncthreads();
    gemm_sub(0, 0);
    gemm_sub(0, 1);

    // ================= encoder (2 barriers/step, half-interleaved pipeline) =================
    for (int t = 0; t < OBS; ++t) {
        __syncthreads();                               // ph A
        f32x2 on0{0.f, 0.f};
        if (t + 1 < OBS) on0 = *(const f32x2*)(obr0 + (t + 1) * 2);
        update_sub(0, 0);                              // consume acc[0] (C0)
        gemm_sub(1, 0);                                // refill acc[0] (C1)
        update_sub(0, 1);                              // consume acc[1] (C0)
        gemm_sub(1, 1);                                // refill acc[1] (C1)
        if (t + 1 < OBS) emb_row(lane, on0[0], on0[1]);
        __syncthreads();                               // ph B
        f32x2 on1{0.f, 0.f};
        if (t + 1 < OBS) on1 = *(const f32x2*)(obr1 + (t + 1) * 2);
        update_sub(1, 0);
        if (t + 1 < OBS) gemm_sub(0, 0);
        update_sub(1, 1);
        if (t + 1 < OBS) {
            gemm_sub(0, 1);
            emb_row(64 + lane, on1[0], on1[1]);
        }
    }

    // ================= decoder =================
    load_bfr(Wih_d, Whh_d);
    load_bias(sw.bcomb_d);
    gemm_sub(0, 0);   // td=0 C0: x = emb(obs[:,19]) already in As; h C0 from enc t=19
    gemm_sub(0, 1);

    auto pred_phase = [&](int chunk, int td) {
        const int prow = chunk * 64 + (tid >> 2);
        const int comp = (tid >> 1) & 1, half = tid & 1;
        const int cb = half * 32;
        float p = 0.f;
        #pragma unroll
        for (int e8 = 0; e8 < 4; ++e8) {
            bf16x8 hv = *(const bf16x8*)&As[prow * AST + 64 + cb + e8 * 8];
            f32x4 w0 = *(const f32x4*)&sw.wfc[comp * 64 + cb + e8 * 8];
            f32x4 w1 = *(const f32x4*)&sw.wfc[comp * 64 + cb + e8 * 8 + 4];
            p += (float)hv[0] * w0[0] + (float)hv[1] * w0[1] + (float)hv[2] * w0[2] + (float)hv[3] * w0[3]
               + (float)hv[4] * w1[0] + (float)hv[5] * w1[1] + (float)hv[6] * w1[2] + (float)hv[7] * w1[3];
        }
        p += __shfl_xor(p, 1, 64);
        if (half == 0) {
            p += sw.bfc[comp];
            pred_s[prow * 2 + comp] = p;
            out[((gRow0 + prow) * PRED + td) * 2 + comp] = p;
        }
    };
    auto emb_dec = [&](int chunk) {
        const int row = chunk * 64 + lane;
        f32x2 pv = *(const f32x2*)&pred_s[row * 2];
        emb_row(row, pv[0], pv[1]);
    };

    for (int td = 0; td < PRED; ++td) {
        __syncthreads();                 // ph1
        update_sub(0, 0);
        gemm_sub(1, 0);
        update_sub(0, 1);
        gemm_sub(1, 1);
        __syncthreads();                 // ph2
        update_sub(1, 0);
        update_sub(1, 1);
        pred_phase(0, td);               // rows 0..63 -> pred_s, out
        __syncthreads();                 // ph3
        pred_phase(1, td);               // rows 64..127
        if (td + 1 < PRED) emb_dec(0);   // x(td+1) rows 0..63
        __syncthreads();                 // ph4
        if (td + 1 < PRED) {
            emb_dec(1);                  // x(td+1) rows 64..127
            gemm_sub(0, 0);
            gemm_sub(0, 1);
        }
    }
}

extern "C" void kernel_launch(void* const* d_in, const int* in_sizes, int n_in,
                              void* d_out, int out_size, void* d_ws, size_t ws_size,
                              hipStream_t stream) {
    (void)in_sizes; (void)n_in; (void)d_ws; (void)ws_size; (void)out_size;
    const float* obs   = (const float*)d_in[0];
    const float* W_emb = (const float*)d_in[1];
    const float* b_emb = (const float*)d_in[2];
    const float* Wih_e = (const float*)d_in[3];
    const float* Whh_e = (const float*)d_in[4];
    const float* bih_e = (const float*)d_in[5];
    const float* bhh_e = (const float*)d_in[6];
    const float* Wih_d = (const float*)d_in[7];
    const float* Whh_d = (const float*)d_in[8];
    const float* bih_d = (const float*)d_in[9];
    const float* bhh_d = (const float*)d_in[10];
    const float* W_fc  = (const float*)d_in[11];
    const float* b_fc  = (const float*)d_in[12];
    float* o = (float*)d_out;

    dim3 grid(BATCH / BT), block(256);
    hipLaunchKernelGGL(vanilla_lstm, grid, block, 0, stream,
                       obs, W_emb, b_emb, Wih_e, Whh_e, bih_e, bhh_e,
                       Wih_d, Whh_d, bih_d, bhh_d, W_fc, b_fc, o);
}